// Round 5
// baseline (67.025 us; speedup 1.0000x reference)
//
#include <hip/hip_runtime.h>

#define NN 16384
#define NT 1024
#define PER 16
#define QCAP 2048

__global__ __launch_bounds__(NT) void dag_eval_kernel(
    const int* __restrict__ left,
    const int* __restrict__ right,
    const unsigned char* __restrict__ reroll_raw,
    int* __restrict__ out)
{
    __shared__ __align__(16) unsigned int  pairs[NN];       // l16 | r16<<16 (64KB)
    __shared__ __align__(16) unsigned char state[NN + 16];  // hs|hr<<1|fin<<2; [NN..]=4
    __shared__ __align__(16) unsigned char reach[NN];       // 0/1 bytes
    __shared__ __align__(16) unsigned char rbits[NN / 8];   // leaf reroll bit table
    __shared__ unsigned short q[2][QCAP];                   // BFS queues
    __shared__ int readyB[16];
    __shared__ int nzmask;
    __shared__ int cnt;

    const int tid  = threadIdx.x;
    const int w    = tid >> 6;
    const int lane = tid & 63;

    if (tid < 16) { readyB[tid] = 0; state[NN + tid] = 4; }
    if (tid == 0) { nzmask = 0; cnt = 0; }

    // ---- stage packed children (ascending, coalesced) ----
    {
        const int4* l4 = (const int4*)left;
        const int4* r4 = (const int4*)right;
        const int base = tid * PER;
        #pragma unroll
        for (int j = 0; j < PER / 4; ++j) {
            int4 a = l4[(base >> 2) + j];
            int4 b = r4[(base >> 2) + j];
            uint4 pk;
            pk.x = (a.x & 0xFFFF) | ((unsigned)b.x << 16);
            pk.y = (a.y & 0xFFFF) | ((unsigned)b.y << 16);
            pk.z = (a.z & 0xFFFF) | ((unsigned)b.z << 16);
            pk.w = (a.w & 0xFFFF) | ((unsigned)b.w << 16);
            *(uint4*)&pairs[base + 4 * j] = pk;
        }
    }

    // ---- own (backward-chunk) children -> registers; wave w owns chunk 15-w ----
    const int own_base = (15 - w) * 1024 + lane * PER;
    unsigned int cpair[PER];
    {
        const int4* l4 = (const int4*)left;
        const int4* r4 = (const int4*)right;
        #pragma unroll
        for (int j = 0; j < PER / 4; ++j) {
            int4 a = l4[(own_base >> 2) + j];
            int4 b = r4[(own_base >> 2) + j];
            cpair[4*j+0] = (a.x & 0xFFFF) | ((unsigned)b.x << 16);
            cpair[4*j+1] = (a.y & 0xFFFF) | ((unsigned)b.y << 16);
            cpair[4*j+2] = (a.z & 0xFFFF) | ((unsigned)b.z << 16);
            cpair[4*j+3] = (a.w & 0xFFFF) | ((unsigned)b.w << 16);
        }
    }

    // ---- leaf_is_reroll layout probe (first 16KB safe for all layouts) ----
    {
        uint4 v = ((const uint4*)reroll_raw)[tid];
        unsigned int t = v.x | v.y | v.z | v.w;
        unsigned int m = 0;
        if (t & 0x000000FFu) m |= 1u;
        if (t & 0x0000FF00u) m |= 2u;
        if (t & 0x00FF0000u) m |= 4u;
        if (t & 0xFF000000u) m |= 8u;
        if (m) atomicOr(&nzmask, (int)m);
    }
    *(uint4*)&reach[tid * PER] = make_uint4(0u, 0u, 0u, 0u);
    __syncthreads();

    // ---- pack reroll bits (2KB table). byte layout iff all 4 byte-lanes hot ----
    {
        const bool bytelay = (nzmask == 0xF) || (nzmask == 0);
        unsigned int m16 = 0;
        if (bytelay) {
            uint4 v = ((const uint4*)reroll_raw)[tid];
            unsigned int wd[4] = {v.x, v.y, v.z, v.w};
            #pragma unroll
            for (int j = 0; j < 4; ++j)
                #pragma unroll
                for (int b = 0; b < 4; ++b)
                    if ((wd[j] >> (8 * b)) & 0xFFu) m16 |= 1u << (4 * j + b);
        } else {
            const uint4* p = (const uint4*)reroll_raw;
            #pragma unroll
            for (int j = 0; j < 4; ++j) {
                uint4 v = p[tid * 4 + j];
                if (v.x) m16 |= 1u << (4 * j + 0);
                if (v.y) m16 |= 1u << (4 * j + 1);
                if (v.z) m16 |= 1u << (4 * j + 2);
                if (v.w) m16 |= 1u << (4 * j + 3);
            }
        }
        ((unsigned short*)rbits)[tid] = (unsigned short)m16;
    }
    if (tid == 0) { reach[0] = 1; q[0][0] = 0; }
    __syncthreads();

    // ---- backward state init from leaf children ----
    int sreg[PER];
    unsigned int unres = 0;
    {
        unsigned int sw[4] = {0, 0, 0, 0};
        #pragma unroll
        for (int k = 0; k < PER; ++k) {
            int c0 = (int)(short)(cpair[k] & 0xFFFF);
            int c1 = (int)(short)(cpair[k] >> 16);
            int s = 0;
            if (c0 < 0) { int id = -c0 - 1; s |= ((rbits[id >> 3] >> (id & 7)) & 1) ? 2 : 1; }
            if (c1 < 0) { int id = -c1 - 1; s |= ((rbits[id >> 3] >> (id & 7)) & 1) ? 2 : 1; }
            if ((c0 < 0 && c1 < 0) || s == 3) s |= 4;
            else unres |= 1u << k;
            sreg[k] = s;
            sw[k >> 2] |= (unsigned)s << (8 * (k & 3));
        }
        *(uint4*)&state[own_base] = make_uint4(sw[0], sw[1], sw[2], sw[3]);
    }
    __syncthreads();   // all staging complete; barrier-free phases begin

    volatile int* rB = readyB;

    // ---- wave 15: forward BFS (single wave, race-free) ----
    if (w == 15) {
        int cur = 0, cn = 1;
        int safety = 600;
        while (cn > 0 && --safety) {
            int nn2 = 0;
            for (int base = 0; base < cn; base += 64) {
                int idx = base + lane;
                bool act = idx < cn;
                int node = act ? (int)q[cur][idx] : 0;
                unsigned int pr = pairs[node];
                int c0 = (int)(short)(pr & 0xFFFF);
                int c1 = (int)(short)(pr >> 16);
                bool p0 = act && c0 > 0 && reach[c0] == 0;
                bool p1 = act && c1 > 0 && reach[c1] == 0;
                if (p0) reach[c0] = (unsigned char)1;
                if (p1) reach[c1] = (unsigned char)1;
                unsigned long long lt = (1ULL << lane) - 1ULL;
                unsigned long long m0 = __ballot(p0);
                if (p0) q[cur ^ 1][nn2 + __popcll(m0 & lt)] = (unsigned short)c0;
                nn2 += __popcll(m0);
                unsigned long long m1 = __ballot(p1);
                if (p1) q[cur ^ 1][nn2 + __popcll(m1 & lt)] = (unsigned short)c1;
                nn2 += __popcll(m1);
                if (nn2 > QCAP - 64) nn2 = QCAP - 64;  // paranoia clamp
                asm volatile("" ::: "memory");
            }
            cur ^= 1; cn = nn2;
        }
    }

    // ---- backward: wave-sequenced descending chunks, no block barriers ----
    if (w > 0) {
        int spins = 0;
        while (rB[w - 1] == 0 && spins < (1 << 17)) { ++spins; __builtin_amdgcn_s_sleep(1); }
    }
    asm volatile("" ::: "memory");
    while (__any(unres != 0)) {
        #pragma unroll
        for (int k = 0; k < PER; ++k) {
            if ((unres >> k) & 1u) {
                int c0 = (int)(short)(cpair[k] & 0xFFFF);
                int c1 = (int)(short)(cpair[k] >> 16);
                int la = (c0 > 0) ? c0 : NN;
                int ra = (c1 > 0) ? c1 : NN;
                int sl = state[la];
                int sr = state[ra];
                int ns = sreg[k] | (sl & 3) | (sr & 3);
                bool fin = ((sl & sr & 4) != 0) || ((ns & 3) == 3);
                if (fin) { ns |= 4; unres &= ~(1u << k); }
                if (ns != sreg[k]) { sreg[k] = ns; state[own_base + k] = (unsigned char)ns; }
            }
        }
        asm volatile("" ::: "memory");
    }
    __threadfence_block();
    if (lane == 0) rB[w] = 1;

    __syncthreads();   // reach + all states final

    // ---- count: sum reach bytes, wave reduce, one atomic per wave ----
    {
        uint4 v = *(const uint4*)&reach[tid * PER];
        unsigned int t = v.x + v.y + v.z + v.w;                 // per-byte sums <= 4
        int cc = (t & 0xFF) + ((t >> 8) & 0xFF) + ((t >> 16) & 0xFF) + (t >> 24);
        #pragma unroll
        for (int off = 32; off; off >>= 1) cc += __shfl_down(cc, off);
        if (lane == 0) atomicAdd(&cnt, cc);
    }

    // ---- outputs ----
    int4* out4 = (int4*)out;
    {
        uint4 v = *(const uint4*)&reach[tid * PER];
        unsigned int wd[4] = {v.x, v.y, v.z, v.w};
        #pragma unroll
        for (int j = 0; j < 4; ++j) {
            int4 a;
            a.x = (wd[j] >> 0)  & 1;
            a.y = (wd[j] >> 8)  & 1;
            a.z = (wd[j] >> 16) & 1;
            a.w = (wd[j] >> 24) & 1;
            out4[(tid * PER >> 2) + j] = a;
        }
    }
    #pragma unroll
    for (int j = 0; j < PER / 4; ++j) {
        int4 h, r;
        h.x =  sreg[4*j+0] & 1;       h.y =  sreg[4*j+1] & 1;
        h.z =  sreg[4*j+2] & 1;       h.w =  sreg[4*j+3] & 1;
        r.x = (sreg[4*j+0] >> 1) & 1; r.y = (sreg[4*j+1] >> 1) & 1;
        r.z = (sreg[4*j+2] >> 1) & 1; r.w = (sreg[4*j+3] >> 1) & 1;
        out4[((NN + own_base) >> 2) + j]     = h;
        out4[((2 * NN + own_base) >> 2) + j] = r;
    }
    __syncthreads();
    if (tid == 0) out[3 * NN] = cnt;
}

extern "C" void kernel_launch(void* const* d_in, const int* in_sizes, int n_in,
                              void* d_out, int out_size, void* d_ws, size_t ws_size,
                              hipStream_t stream)
{
    const int* left  = (const int*)d_in[3];
    const int* right = (const int*)d_in[4];
    const unsigned char* reroll = (const unsigned char*)d_in[5];
    int* out = (int*)d_out;
    dag_eval_kernel<<<1, NT, 0, stream>>>(left, right, reroll, out);
}

// Round 6
// 32.835 us; speedup vs baseline: 2.0413x; 2.0413x over previous
//
#include <hip/hip_runtime.h>

#define NN 16384
#define NT 1024
#define PER 16

__global__ __launch_bounds__(NT) void dag_eval_kernel(
    const int* __restrict__ left,
    const int* __restrict__ right,
    const unsigned char* __restrict__ reroll_raw,
    int* __restrict__ out)
{
    __shared__ __align__(16) unsigned char reach[NN];       // 0/1 bytes
    __shared__ __align__(16) unsigned char state[NN + 16];  // hs|hr<<1|fin<<2; [NN..]=4
    __shared__ int flags[4];
    __shared__ int nzmask;
    __shared__ int cnt;

    const int tid = threadIdx.x;
    const int b0  = tid * PER;

    if (tid < 4)  flags[tid] = 0;
    if (tid == 0) { nzmask = 0; cnt = 0; }
    if (tid < 16) state[NN + tid] = 4;

    // ---- children -> registers (coalesced int4), packed l16 | r16<<16 ----
    unsigned int cpair[PER];
    {
        const int4* l4 = (const int4*)left;
        const int4* r4 = (const int4*)right;
        #pragma unroll
        for (int j = 0; j < PER / 4; ++j) {
            int4 a = l4[(b0 >> 2) + j];
            int4 b = r4[(b0 >> 2) + j];
            cpair[4*j+0] = (a.x & 0xFFFFu) | ((unsigned)b.x << 16);
            cpair[4*j+1] = (a.y & 0xFFFFu) | ((unsigned)b.y << 16);
            cpair[4*j+2] = (a.z & 0xFFFFu) | ((unsigned)b.z << 16);
            cpair[4*j+3] = (a.w & 0xFFFFu) | ((unsigned)b.w << 16);
        }
    }

    // ---- leaf_is_reroll layout probe (first 16 KB safe for all layouts) ----
    {
        uint4 v = ((const uint4*)reroll_raw)[tid];
        unsigned int t = v.x | v.y | v.z | v.w;
        unsigned int m = 0;
        if (t & 0x000000FFu) m |= 1u;
        if (t & 0x0000FF00u) m |= 2u;
        if (t & 0x00FF0000u) m |= 4u;
        if (t & 0xFF000000u) m |= 8u;
        if (m) atomicOr(&nzmask, (int)m);
    }
    *(uint4*)&reach[b0] = make_uint4(0u, 0u, 0u, 0u);
    __syncthreads();

    const int mask   = nzmask;
    const int layout = ((mask & ~1) == 0) ? 0 : (((mask & 3) == 0) ? 1 : 2);
    const int*   ri = (const int*)reroll_raw;
    const float* rf = (const float*)reroll_raw;

    // ---- backward state init from leaf children ----
    int sreg[PER];
    unsigned int todo = 0;
    #pragma unroll
    for (int k = 0; k < PER; ++k) {
        int c0 = (int)(short)(cpair[k] & 0xFFFFu);
        int c1 = (int)(short)(cpair[k] >> 16);
        int s = 0;
        if (c0 < 0) {
            int id = -c0 - 1;
            bool rr = (layout == 2) ? (reroll_raw[id] != 0)
                     : (layout == 1) ? (rf[id] != 0.0f)
                                     : (ri[id] != 0);
            s |= rr ? 2 : 1;
        }
        if (c1 < 0) {
            int id = -c1 - 1;
            bool rr = (layout == 2) ? (reroll_raw[id] != 0)
                     : (layout == 1) ? (rf[id] != 0.0f)
                                     : (ri[id] != 0);
            s |= rr ? 2 : 1;
        }
        if ((c0 < 0 && c1 < 0) || s == 3) s |= 4;
        else todo |= 1u << k;
        sreg[k] = s;
        state[b0 + k] = (unsigned char)s;
    }
    if (tid == 0) reach[0] = 1;
    __syncthreads();

    // ---- merged fixpoint: fwd push-once + bwd pull; 1 barrier/sweep ----
    unsigned int pushed = 0, mm = 0;
    for (int w = 0; w < 4096; ++w) {
        bool ch = false;

        // forward: one ds_read_b128 + movemask + push-once (static unroll)
        uint4 rv = *(const uint4*)&reach[b0];
        mm  =  ((rv.x * 0x01020408u) >> 24) & 0xFu;
        mm |= (((rv.y * 0x01020408u) >> 24) & 0xFu) << 4;
        mm |= (((rv.z * 0x01020408u) >> 24) & 0xFu) << 8;
        mm |= (((rv.w * 0x01020408u) >> 24) & 0xFu) << 12;
        unsigned int newp = mm & ~pushed;
        if (newp) {
            pushed |= newp;
            ch = true;
            #pragma unroll
            for (int k = 0; k < PER; ++k) {
                if ((newp >> k) & 1u) {
                    int c0 = (int)(short)(cpair[k] & 0xFFFFu);
                    int c1 = (int)(short)(cpair[k] >> 16);
                    if (c0 > 0) reach[c0] = (unsigned char)1;
                    if (c1 > 0) reach[c1] = (unsigned char)1;
                }
            }
        }

        // backward: gather-then-combine, todo-masked, static unroll
        if (todo) {
            int tl[PER], tr[PER];
            #pragma unroll
            for (int k = 0; k < PER; ++k) {
                bool act = (todo >> k) & 1u;
                int c0 = (int)(short)(cpair[k] & 0xFFFFu);
                int c1 = (int)(short)(cpair[k] >> 16);
                int la = (act && c0 > 0) ? c0 : NN;
                int ra = (act && c1 > 0) ? c1 : NN;
                tl[k] = state[la];
                tr[k] = state[ra];
            }
            #pragma unroll
            for (int k = 0; k < PER; ++k) {
                if ((todo >> k) & 1u) {
                    int sl = tl[k], sr = tr[k];
                    int ns = sreg[k] | (sl & 3) | (sr & 3);
                    bool fin = ((sl & sr & 4) != 0) || ((ns & 3) == 3);
                    if (fin) { ns |= 4; todo &= ~(1u << k); }
                    if (ns != sreg[k]) {
                        sreg[k] = ns;
                        state[b0 + k] = (unsigned char)ns;
                        ch = true;
                    }
                }
            }
        }

        if (ch) flags[w & 3] = 1;
        __syncthreads();                 // single barrier per sweep
        int f = flags[w & 3];
        if (tid == 0) flags[(w + 2) & 3] = 0;   // safe: >=1 barrier before reuse
        if (!f) break;
    }

    // ---- count: wave shuffle reduce, one atomic per wave ----
    int cc = __popc(mm);
    #pragma unroll
    for (int off = 32; off; off >>= 1) cc += __shfl_down(cc, off);
    if ((tid & 63) == 0) atomicAdd(&cnt, cc);

    // ---- outputs from registers, int4 stores ----
    int4* out4 = (int4*)out;
    #pragma unroll
    for (int j = 0; j < PER / 4; ++j) {
        int4 a, h, r;
        a.x = (mm >> (4*j+0)) & 1; a.y = (mm >> (4*j+1)) & 1;
        a.z = (mm >> (4*j+2)) & 1; a.w = (mm >> (4*j+3)) & 1;
        h.x =  sreg[4*j+0] & 1;       h.y =  sreg[4*j+1] & 1;
        h.z =  sreg[4*j+2] & 1;       h.w =  sreg[4*j+3] & 1;
        r.x = (sreg[4*j+0] >> 1) & 1; r.y = (sreg[4*j+1] >> 1) & 1;
        r.z = (sreg[4*j+2] >> 1) & 1; r.w = (sreg[4*j+3] >> 1) & 1;
        out4[(b0 >> 2) + j]            = a;
        out4[((NN + b0) >> 2) + j]     = h;
        out4[((2 * NN + b0) >> 2) + j] = r;
    }
    __syncthreads();
    if (tid == 0) out[3 * NN] = cnt;
}

extern "C" void kernel_launch(void* const* d_in, const int* in_sizes, int n_in,
                              void* d_out, int out_size, void* d_ws, size_t ws_size,
                              hipStream_t stream)
{
    const int* left  = (const int*)d_in[3];
    const int* right = (const int*)d_in[4];
    const unsigned char* reroll = (const unsigned char*)d_in[5];
    int* out = (int*)d_out;
    dag_eval_kernel<<<1, NT, 0, stream>>>(left, right, reroll, out);
}